// Round 1
// baseline (2240.202 us; speedup 1.0000x reference)
//
#include <hip/hip_runtime.h>

#define H 128
#define F_IN 16
#define SA_RS 132   // LDS A-tile row stride (f32): 64 rows x 128 k (+4 pad)
#define SW_RS 68    // LDS W-tile row stride (f32): 128 j rows x 64 k (+4 pad), transposed

// ---------------------------------------------------------------------------
// Stage a 64x128 f32 tile (rows r0..r0+63 of src[M,128]) into LDS row-major.
// Rows >= M are zero-filled.
__device__ __forceinline__ void stage_tile(const float* src, float* sA,
                                           int r0, int M, int t)
{
#pragma unroll
    for (int i = 0; i < 8; ++i) {
        int f  = t + 256 * i;
        int m  = f >> 5;
        int c4 = f & 31;
        int row = r0 + m;
        float4 v = make_float4(0.f, 0.f, 0.f, 0.f);
        if (row < M)
            v = *reinterpret_cast<const float4*>(src + (size_t)row * H + c4 * 4);
        *reinterpret_cast<float4*>(sA + m * SA_RS + c4 * 4) = v;
    }
}

// ---------------------------------------------------------------------------
// acc[4][8] += sA(64x128) @ W(128x128 row-major, global).
// W is staged in two 64-row chunks, transposed into sW[j][k].
// Thread t owns rows m0..m0+3 (m0=(t>>4)*4) and cols j = (t&15)+16*q.
// NOTE: begins with __syncthreads() (covers caller's sA staging); does NOT
// end with one (caller must sync before reusing sA/sW).
__device__ __forceinline__ void gemm_core(const float* __restrict__ W,
                                          const float* sA, float* sW,
                                          float acc[4][8], int t)
{
    const int tx = t & 15;
    const int m0 = (t >> 4) * 4;
#pragma unroll
    for (int c = 0; c < 2; ++c) {
        __syncthreads();
        // stage W rows c*64 .. c*64+63, transposed
#pragma unroll
        for (int i = 0; i < 8; ++i) {
            int f  = t + 256 * i;
            int kl = f >> 5;
            int j4 = f & 31;
            float4 w4 = *reinterpret_cast<const float4*>(W + (size_t)(c * 64 + kl) * H + j4 * 4);
            sW[(4 * j4 + 0) * SW_RS + kl] = w4.x;
            sW[(4 * j4 + 1) * SW_RS + kl] = w4.y;
            sW[(4 * j4 + 2) * SW_RS + kl] = w4.z;
            sW[(4 * j4 + 3) * SW_RS + kl] = w4.w;
        }
        __syncthreads();
        for (int k4 = 0; k4 < 16; ++k4) {
            float4 a[4];
#pragma unroll
            for (int r = 0; r < 4; ++r)
                a[r] = *reinterpret_cast<const float4*>(sA + (m0 + r) * SA_RS + c * 64 + k4 * 4);
#pragma unroll
            for (int q = 0; q < 8; ++q) {
                const float4 w = *reinterpret_cast<const float4*>(sW + (tx + 16 * q) * SW_RS + k4 * 4);
#pragma unroll
                for (int r = 0; r < 4; ++r)
                    acc[r][q] += a[r].x * w.x + a[r].y * w.y + a[r].z * w.z + a[r].w * w.w;
            }
        }
    }
}

__device__ __forceinline__ void zero_acc(float acc[4][8])
{
#pragma unroll
    for (int r = 0; r < 4; ++r)
#pragma unroll
        for (int q = 0; q < 8; ++q) acc[r][q] = 0.f;
}

// ---------------------------------------------------------------------------
// Encoder: out = relu(X[M,16] @ W[16,128] + b)
__global__ __launch_bounds__(256) void enc_kernel(const float* __restrict__ X,
                                                  const float* __restrict__ W,
                                                  const float* __restrict__ bias,
                                                  float* __restrict__ out, int M)
{
    __shared__ float sW[F_IN * H];
    __shared__ float sb[H];
    int t = threadIdx.x;
    reinterpret_cast<float4*>(sW)[t]       = reinterpret_cast<const float4*>(W)[t];
    reinterpret_cast<float4*>(sW)[t + 256] = reinterpret_cast<const float4*>(W)[t + 256];
    if (t < H) sb[t] = bias[t];
    __syncthreads();
    int row = blockIdx.x * 2 + (t >> 7);
    if (row >= M) return;
    int j = t & 127;
    float acc = sb[j];
#pragma unroll
    for (int k = 0; k < F_IN; ++k)
        acc += X[(size_t)row * F_IN + k] * sW[k * H + j];
    out[(size_t)row * H + j] = fmaxf(acc, 0.f);
}

// ---------------------------------------------------------------------------
// ABP: A = h@W1, B = h@W2, P = h@U1 (selected by blockIdx.y)
__global__ __launch_bounds__(256) void abp_kernel(const float* __restrict__ h,
                                                  const float* __restrict__ eW,
                                                  const float* __restrict__ n1W,
                                                  float* __restrict__ Aout,
                                                  float* __restrict__ Bout,
                                                  float* __restrict__ Pout, int M)
{
    __shared__ float sA[64 * SA_RS];
    __shared__ float sW[H * SW_RS];
    int t  = threadIdx.x;
    int r0 = blockIdx.x * 64;
    const float* W;
    float* C;
    if (blockIdx.y == 0)      { W = eW;         C = Aout; }
    else if (blockIdx.y == 1) { W = eW + H * H; C = Bout; }
    else                      { W = n1W;        C = Pout; }
    stage_tile(h, sA, r0, M, t);
    float acc[4][8];
    zero_acc(acc);
    gemm_core(W, sA, sW, acc, t);
    int tx = t & 15, m0 = (t >> 4) * 4;
#pragma unroll
    for (int r = 0; r < 4; ++r) {
        int row = r0 + m0 + r;
        if (row < M) {
#pragma unroll
            for (int q = 0; q < 8; ++q)
                C[(size_t)row * H + tx + 16 * q] = acc[r][q];
        }
    }
}

// ---------------------------------------------------------------------------
// Fused edge kernel (e updated IN PLACE; per-block row ownership makes this safe):
//   e'    = relu(e@W3 + A[row] + B[col] + be)
//   m     = relu(e'@U2 + P[row] + b1)
//   aggsum[col] += m ; cnt[col] += 1
__global__ __launch_bounds__(256) void edge_kernel(float* eb,
                                                   const int* __restrict__ row_idx,
                                                   const int* __restrict__ col_idx,
                                                   const float* __restrict__ Asrc,
                                                   const float* __restrict__ Bsrc,
                                                   const float* __restrict__ Psrc,
                                                   const float* __restrict__ W3,
                                                   const float* __restrict__ U2,
                                                   const float* __restrict__ be,
                                                   const float* __restrict__ b1,
                                                   float* __restrict__ aggsum,
                                                   float* __restrict__ cnt, int E)
{
    __shared__ float sA[64 * SA_RS];
    __shared__ float sW[H * SW_RS];
    int t  = threadIdx.x;
    int e0 = blockIdx.x * 64;
    stage_tile(eb, sA, e0, E, t);
    float acc[4][8];
    zero_acc(acc);
    gemm_core(W3, sA, sW, acc, t);

    int tx = t & 15, m0 = (t >> 4) * 4;
    int rows[4], cols[4];
#pragma unroll
    for (int r = 0; r < 4; ++r) {
        int ge  = e0 + m0 + r;
        int gec = (ge < E) ? ge : 0;
        rows[r] = row_idx[gec];
        cols[r] = col_idx[gec];
    }
    float enew[4][8];
#pragma unroll
    for (int r = 0; r < 4; ++r) {
        int ge = e0 + m0 + r;
#pragma unroll
        for (int q = 0; q < 8; ++q) {
            int j = tx + 16 * q;
            float v = acc[r][q] + Asrc[(size_t)rows[r] * H + j]
                                + Bsrc[(size_t)cols[r] * H + j] + be[j];
            v = fmaxf(v, 0.f);
            enew[r][q] = v;
            if (ge < E) eb[(size_t)ge * H + j] = v;
        }
    }
    __syncthreads();   // all phase-1 reads of sA done -> safe to overwrite
#pragma unroll
    for (int r = 0; r < 4; ++r)
#pragma unroll
        for (int q = 0; q < 8; ++q)
            sA[(m0 + r) * SA_RS + tx + 16 * q] = enew[r][q];

    zero_acc(acc);
    gemm_core(U2, sA, sW, acc, t);
#pragma unroll
    for (int r = 0; r < 4; ++r) {
        int ge = e0 + m0 + r;
        if (ge < E) {
#pragma unroll
            for (int q = 0; q < 8; ++q) {
                int j = tx + 16 * q;
                float v = acc[r][q] + Psrc[(size_t)rows[r] * H + j] + b1[j];
                v = fmaxf(v, 0.f);
                atomicAdd(&aggsum[(size_t)cols[r] * H + j], v);
            }
            if (tx == 0) atomicAdd(&cnt[cols[r]], 1.f);
        }
    }
}

// ---------------------------------------------------------------------------
// Node update (in place): h = relu(h@V1 + (aggsum/max(cnt,1))@V2 + b2)
__global__ __launch_bounds__(256) void node_kernel(float* hb,
                                                   const float* __restrict__ aggsum,
                                                   const float* __restrict__ cnt,
                                                   const float* __restrict__ V,
                                                   const float* __restrict__ b2, int M)
{
    __shared__ float sA[64 * SA_RS];
    __shared__ float sW[H * SW_RS];
    int t  = threadIdx.x;
    int r0 = blockIdx.x * 64;
    stage_tile(hb, sA, r0, M, t);
    float acc[4][8];
    zero_acc(acc);
    gemm_core(V, sA, sW, acc, t);
    __syncthreads();   // phase-1 sA reads done
#pragma unroll
    for (int i = 0; i < 8; ++i) {
        int f  = t + 256 * i;
        int m  = f >> 5;
        int c4 = f & 31;
        int row = r0 + m;
        float4 v = make_float4(0.f, 0.f, 0.f, 0.f);
        if (row < M) {
            float4 s = *reinterpret_cast<const float4*>(aggsum + (size_t)row * H + c4 * 4);
            float inv = 1.f / fmaxf(cnt[row], 1.f);
            v = make_float4(s.x * inv, s.y * inv, s.z * inv, s.w * inv);
        }
        *reinterpret_cast<float4*>(sA + m * SA_RS + c4 * 4) = v;
    }
    gemm_core(V + H * H, sA, sW, acc, t);
    int tx = t & 15, m0 = (t >> 4) * 4;
#pragma unroll
    for (int r = 0; r < 4; ++r) {
        int row = r0 + m0 + r;
        if (row < M) {
#pragma unroll
            for (int q = 0; q < 8; ++q) {
                int j = tx + 16 * q;
                hb[(size_t)row * H + j] = fmaxf(acc[r][q] + b2[j], 0.f);
            }
        }
    }
}

// ---------------------------------------------------------------------------
// Column sums + sums of squares over v[M,128] -> atomics into sums[0:128]=Σv,
// sums[128:256]=Σv².
__global__ __launch_bounds__(256) void stats_kernel(const float* __restrict__ v,
                                                    int M, float* __restrict__ sums)
{
    __shared__ float red[512];
    int t = threadIdx.x;
    int j = t & 127, half = t >> 7;
    float s = 0.f, s2 = 0.f;
    for (int row = blockIdx.x * 2 + half; row < M; row += gridDim.x * 2) {
        float x = v[(size_t)row * H + j];
        s += x;
        s2 += x * x;
    }
    red[t] = s;
    red[256 + t] = s2;
    __syncthreads();
    if (t < 128) {
        atomicAdd(&sums[j],     red[t] + red[t + 128]);
        atomicAdd(&sums[H + j], red[256 + t] + red[384 + t]);
    }
}

// ---------------------------------------------------------------------------
// BatchNorm apply (training-mode batch stats), in place.
__global__ __launch_bounds__(256) void bn_kernel(float* __restrict__ v, int M,
                                                 const float* __restrict__ sums,
                                                 const float* __restrict__ g,
                                                 const float* __restrict__ b)
{
    const float invM = 1.f / (float)M;
    size_t total4 = (size_t)M * 32;
    for (size_t i = (size_t)blockIdx.x * 256 + threadIdx.x; i < total4;
         i += (size_t)gridDim.x * 256) {
        int j0 = (int)(i & 31) * 4;
        float4 x = reinterpret_cast<float4*>(v)[i];
        float* px = &x.x;
#pragma unroll
        for (int c = 0; c < 4; ++c) {
            int j = j0 + c;
            float mean = sums[j] * invM;
            float var  = sums[H + j] * invM - mean * mean;
            float sc   = rsqrtf(var + 1e-5f) * g[j];
            px[c] = (px[c] - mean) * sc + b[j];
        }
        reinterpret_cast<float4*>(v)[i] = x;
    }
}

// ---------------------------------------------------------------------------
// Final readout: out = [mean(h) | mean(e)] @ reg_w + reg_b
__global__ __launch_bounds__(256) void final_kernel(const float* __restrict__ hsum,
                                                    const float* __restrict__ esum,
                                                    const float* __restrict__ reg_w,
                                                    const float* __restrict__ reg_b,
                                                    float* __restrict__ out,
                                                    float invN, float invE)
{
    __shared__ float red[256];
    int t = threadIdx.x;
    float v = (t < 128) ? hsum[t] * invN * reg_w[t]
                        : esum[t - 128] * invE * reg_w[t];
    red[t] = v;
    __syncthreads();
    for (int s = 128; s > 0; s >>= 1) {
        if (t < s) red[t] += red[t + s];
        __syncthreads();
    }
    if (t == 0) out[0] = red[0] + reg_b[0];
}

// ---------------------------------------------------------------------------
extern "C" void kernel_launch(void* const* d_in, const int* in_sizes, int n_in,
                              void* d_out, int out_size, void* d_ws, size_t ws_size,
                              hipStream_t stream)
{
    const float* x          = (const float*)d_in[0];
    const int*   edge_index = (const int*)  d_in[1];
    const float* edge_attr  = (const float*)d_in[2];
    const float* enc_node_w = (const float*)d_in[3];
    const float* enc_node_b = (const float*)d_in[4];
    const float* enc_edge_w = (const float*)d_in[5];
    const float* enc_edge_b = (const float*)d_in[6];
    const float* edge_w     = (const float*)d_in[7];
    const float* edge_b     = (const float*)d_in[8];
    const float* n1_w       = (const float*)d_in[9];
    const float* n1_b       = (const float*)d_in[10];
    const float* n2_w       = (const float*)d_in[11];
    const float* n2_b       = (const float*)d_in[12];
    const float* bn_node_g  = (const float*)d_in[13];
    const float* bn_node_b  = (const float*)d_in[14];
    const float* bn_edge_g  = (const float*)d_in[15];
    const float* bn_edge_b  = (const float*)d_in[16];
    const float* reg_w      = (const float*)d_in[17];
    const float* reg_b      = (const float*)d_in[18];

    const int N = in_sizes[0] / F_IN;
    const int E = in_sizes[1] / 2;
    const size_t NH = (size_t)N * H;
    const size_t EH = (size_t)E * H;

    float* ws     = (float*)d_ws;
    float* hbuf   = ws;                 // [N,128]  (in place across layers)
    float* ebuf   = hbuf + NH;          // [E,128]  (in place across layers)
    float* Abuf   = ebuf + EH;          // [N,128]
    float* Bbuf   = Abuf + NH;          // [N,128]
    float* Pbuf   = Bbuf + NH;          // [N,128]
    float* aggsum = Pbuf + NH;          // [N,128]
    float* cnt    = aggsum + NH;        // [N]
    float* stats  = cnt + N;            // hsum[128], hsumsq[128], esum[128], esumsq[128]

    const int* row_idx = edge_index;
    const int* col_idx = edge_index + E;

    enc_kernel<<<(N + 1) / 2, 256, 0, stream>>>(x, enc_node_w, enc_node_b, hbuf, N);
    enc_kernel<<<(E + 1) / 2, 256, 0, stream>>>(edge_attr, enc_edge_w, enc_edge_b, ebuf, E);

    const int nodeBlocks = (N + 63) / 64;
    const int edgeBlocks = (E + 63) / 64;

    for (int i = 0; i < 3; ++i) {
        // zero aggsum + cnt + stats (contiguous)
        hipMemsetAsync(aggsum, 0, (NH + (size_t)N + 512) * sizeof(float), stream);
        abp_kernel<<<dim3(nodeBlocks, 3), 256, 0, stream>>>(
            hbuf, edge_w + (size_t)i * 384 * H, n1_w + (size_t)i * 256 * H,
            Abuf, Bbuf, Pbuf, N);
        edge_kernel<<<edgeBlocks, 256, 0, stream>>>(
            ebuf, row_idx, col_idx, Abuf, Bbuf, Pbuf,
            edge_w + (size_t)i * 384 * H + 256 * H,
            n1_w + (size_t)i * 256 * H + 128 * H,
            edge_b + i * H, n1_b + i * H,
            aggsum, cnt, E);
        node_kernel<<<nodeBlocks, 256, 0, stream>>>(
            hbuf, aggsum, cnt, n2_w + (size_t)i * 256 * H, n2_b + i * H, N);
        stats_kernel<<<512, 256, 0, stream>>>(hbuf, N, stats);
        stats_kernel<<<512, 256, 0, stream>>>(ebuf, E, stats + 256);
        if (i < 2) {
            bn_kernel<<<1024, 256, 0, stream>>>(hbuf, N, stats,       bn_node_g, bn_node_b);
            bn_kernel<<<2048, 256, 0, stream>>>(ebuf, E, stats + 256, bn_edge_g, bn_edge_b);
        }
    }
    final_kernel<<<1, 256, 0, stream>>>(stats, stats + 256, reg_w, reg_b,
                                        (float*)d_out, 1.f / (float)N, 1.f / (float)E);
}

// Round 5
// 1756.055 us; speedup vs baseline: 1.2757x; 1.2757x over previous
//
#include <hip/hip_runtime.h>

#define H 128
#define F_IN 16

typedef __attribute__((ext_vector_type(8))) short short8;
typedef __attribute__((ext_vector_type(4))) float f32x4;

// f32 -> bf16 round-to-nearest-even
__device__ __forceinline__ unsigned short f2bf(float f)
{
    unsigned u = __builtin_bit_cast(unsigned, f);
    u += 0x7FFFu + ((u >> 16) & 1u);
    return (unsigned short)(u >> 16);
}
__device__ __forceinline__ float bf2f(unsigned short h)
{
    return __builtin_bit_cast(float, (unsigned)h << 16);
}
struct BfPair { short hi, lo; };
// Exact split: x ≈ bf2f(hi) + bf2f(lo), residual ~2^-18 |x|
__device__ __forceinline__ BfPair split2(float x)
{
    BfPair p;
    unsigned short h = f2bf(x);
    p.hi = (short)h;
    p.lo = (short)f2bf(x - bf2f(h));
    return p;
}

// ---------------------------------------------------------------------------
// Stage a 64x128 f32 tile as split bf16 (hi/lo) into swizzled LDS:
//   element (row,k) -> ushort index  row*128 + (k ^ ((row&7)<<3))
__device__ __forceinline__ void stage_split(const float* __restrict__ src,
                                            unsigned short* sH, unsigned short* sL,
                                            int r0, int M, int t)
{
#pragma unroll
    for (int i = 0; i < 4; ++i) {
        int cid  = t + 256 * i;          // 1024 chunks = 64 rows * 16 chunks
        int row  = cid >> 4;
        int ck   = cid & 15;
        int grow = r0 + row;
        short8 ph = (short8)0, pl = (short8)0;
        if (grow < M) {
            const float4* q = (const float4*)(src + (size_t)grow * H + ck * 8);
            float4 a = q[0], b = q[1];
            float xs[8] = {a.x, a.y, a.z, a.w, b.x, b.y, b.z, b.w};
#pragma unroll
            for (int j = 0; j < 8; ++j) {
                BfPair p = split2(xs[j]);
                ph[j] = p.hi;
                pl[j] = p.lo;
            }
        }
        int addr = (row << 7) + ((ck ^ (row & 7)) << 3);
        *(short8*)(sH + addr) = ph;
        *(short8*)(sL + addr) = pl;
    }
}

// Same, but value = aggsum[row][k] / max(cnt[row],1)
__device__ __forceinline__ void stage_agg_split(const float* __restrict__ aggsum,
                                                const float* __restrict__ cnt,
                                                unsigned short* sH, unsigned short* sL,
                                                int r0, int M, int t)
{
#pragma unroll
    for (int i = 0; i < 4; ++i) {
        int cid  = t + 256 * i;
        int row  = cid >> 4;
        int ck   = cid & 15;
        int grow = r0 + row;
        short8 ph = (short8)0, pl = (short8)0;
        if (grow < M) {
            const float4* q = (const float4*)(aggsum + (size_t)grow * H + ck * 8);
            float4 a = q[0], b = q[1];
            float inv = 1.f / fmaxf(cnt[grow], 1.f);
            float xs[8] = {a.x * inv, a.y * inv, a.z * inv, a.w * inv,
                           b.x * inv, b.y * inv, b.z * inv, b.w * inv};
#pragma unroll
            for (int j = 0; j < 8; ++j) {
                BfPair p = split2(xs[j]);
                ph[j] = p.hi;
                pl[j] = p.lo;
            }
        }
        int addr = (row << 7) + ((ck ^ (row & 7)) << 3);
        *(short8*)(sH + addr) = ph;
        *(short8*)(sL + addr) = pl;
    }
}

// ---------------------------------------------------------------------------
// Load split B-operand fragments for weight W (f32 [128][128]) covering cols
// jb..jb+31. Lane holds B[k=32s+8g+j][jb+16c+(lane&15)]
__device__ __forceinline__ void load_wfrag_split(const float* __restrict__ W, int jb,
                                                 int lane, short8 wfh[4][2], short8 wfl[4][2])
{
    const int g = lane >> 4, c0 = lane & 15;
#pragma unroll
    for (int s = 0; s < 4; ++s)
#pragma unroll
        for (int c = 0; c < 2; ++c) {
            short8 fh, fl;
#pragma unroll
            for (int j = 0; j < 8; ++j) {
                int k = 32 * s + 8 * g + j;
                BfPair p = split2(W[(size_t)k * H + jb + 16 * c + c0]);
                fh[j] = p.hi;
                fl[j] = p.lo;
            }
            wfh[s][c] = fh;
            wfl[s][c] = fl;
        }
}

// acc += (sH+sL) @ (Wh+Wl) via 3 MFMA products (al@wl term ~2^-18, dropped)
__device__ __forceinline__ void mfma_gemm3(const unsigned short* sH, const unsigned short* sL,
                                           const short8 wfh[4][2], const short8 wfl[4][2],
                                           f32x4 acc[4][2], int lane)
{
    const int g = lane >> 4, r = lane & 15;
#pragma unroll
    for (int s = 0; s < 4; ++s) {
        short8 ah[4], al[4];
#pragma unroll
        for (int fr = 0; fr < 4; ++fr) {
            int row  = 16 * fr + r;
            int ck   = (4 * s + g) ^ (row & 7);
            int addr = (row << 7) + (ck << 3);
            ah[fr] = *(const short8*)(sH + addr);
            al[fr] = *(const short8*)(sL + addr);
        }
#pragma unroll
        for (int fr = 0; fr < 4; ++fr)
#pragma unroll
            for (int c = 0; c < 2; ++c) {
                f32x4 a = acc[fr][c];
                a = __builtin_amdgcn_mfma_f32_16x16x32_bf16(ah[fr], wfh[s][c], a, 0, 0, 0);
                a = __builtin_amdgcn_mfma_f32_16x16x32_bf16(al[fr], wfh[s][c], a, 0, 0, 0);
                a = __builtin_amdgcn_mfma_f32_16x16x32_bf16(ah[fr], wfl[s][c], a, 0, 0, 0);
                acc[fr][c] = a;
            }
    }
}

__device__ __forceinline__ void zero_acc(f32x4 acc[4][2])
{
#pragma unroll
    for (int fr = 0; fr < 4; ++fr)
#pragma unroll
        for (int c = 0; c < 2; ++c) {
            acc[fr][c][0] = 0.f; acc[fr][c][1] = 0.f;
            acc[fr][c][2] = 0.f; acc[fr][c][3] = 0.f;
        }
}

// ---------------------------------------------------------------------------
// Encoder: out = relu(X[M,16] @ W[16,128] + b)   (pure f32, K=16)
__global__ __launch_bounds__(256) void enc_kernel(const float* __restrict__ X,
                                                  const float* __restrict__ W,
                                                  const float* __restrict__ bias,
                                                  float* __restrict__ out, int M)
{
    __shared__ float sW[F_IN * H];
    __shared__ float sb[H];
    int t = threadIdx.x;
    reinterpret_cast<float4*>(sW)[t]       = reinterpret_cast<const float4*>(W)[t];
    reinterpret_cast<float4*>(sW)[t + 256] = reinterpret_cast<const float4*>(W)[t + 256];
    if (t < H) sb[t] = bias[t];
    __syncthreads();
    int row = blockIdx.x * 2 + (t >> 7);
    if (row >= M) return;
    int j = t & 127;
    float acc = sb[j];
#pragma unroll
    for (int k = 0; k < F_IN; ++k)
        acc += X[(size_t)row * F_IN + k] * sW[k * H + j];
    out[(size_t)row * H + j] = fmaxf(acc, 0.f);
}

// ---------------------------------------------------------------------------
// ABP: A = h@W1, B = h@W2, P = h@U1 (raw). One staged split h-tile, 3 GEMMs.
__global__ __launch_bounds__(256) void abp_kernel(const float* __restrict__ hb,
                                                  const float* __restrict__ eW,
                                                  const float* __restrict__ n1W,
                                                  float* __restrict__ Aout,
                                                  float* __restrict__ Bout,
                                                  float* __restrict__ Pout, int M)
{
    __shared__ __align__(16) unsigned short sAh[64 * 128];
    __shared__ __align__(16) unsigned short sAl[64 * 128];
    const int t = threadIdx.x, lane = t & 63, w = t >> 6, jb = 32 * w;
    const int r0 = blockIdx.x * 64;
    stage_split(hb, sAh, sAl, r0, M, t);
    __syncthreads();
    const int g = lane >> 4, c0 = lane & 15;
    short8 wfh[4][2], wfl[4][2];
    f32x4  acc[4][2];
#pragma unroll
    for (int p = 0; p < 3; ++p) {
        const float* W = (p == 0) ? eW : (p == 1) ? eW + H * H : n1W;
        float* C       = (p == 0) ? Aout : (p == 1) ? Bout : Pout;
        load_wfrag_split(W, jb, lane, wfh, wfl);
        zero_acc(acc);
        mfma_gemm3(sAh, sAl, wfh, wfl, acc, lane);
#pragma unroll
        for (int fr = 0; fr < 4; ++fr)
#pragma unroll
            for (int c = 0; c < 2; ++c) {
                int j = jb + 16 * c + c0;
#pragma unroll
                for (int r = 0; r < 4; ++r) {
                    int row = r0 + 16 * fr + 4 * g + r;
                    if (row < M) C[(size_t)row * H + j] = acc[fr][c][r];
                }
            }
    }
}

// ---------------------------------------------------------------------------
// Fused edge kernel (e updated IN PLACE; per-block row ownership):
//   e' = relu(e@W3 + A[row] + B[col] + be)
//   m  = relu(e'@U2 + P[row] + b1); aggsum[col] += m; cnt[col] += 1 (wave 0 only!)
__global__ __launch_bounds__(256) void edge_kernel(float* eb,
                                                   const int* __restrict__ row_idx,
                                                   const int* __restrict__ col_idx,
                                                   const float* __restrict__ Asrc,
                                                   const float* __restrict__ Bsrc,
                                                   const float* __restrict__ Psrc,
                                                   const float* __restrict__ W3,
                                                   const float* __restrict__ U2,
                                                   const float* __restrict__ be,
                                                   const float* __restrict__ b1,
                                                   float* __restrict__ aggsum,
                                                   float* __restrict__ cnt, int E)
{
    __shared__ __align__(16) unsigned short sAh[64 * 128];
    __shared__ __align__(16) unsigned short sAl[64 * 128];
    __shared__ __align__(16) unsigned short sBh[64 * 128];
    __shared__ __align__(16) unsigned short sBl[64 * 128];
    const int t = threadIdx.x, lane = t & 63, w = t >> 6, jb = 32 * w;
    const int e0 = blockIdx.x * 64;
    stage_split(eb, sAh, sAl, e0, E, t);
    const int g = lane >> 4, c0 = lane & 15;
    short8 wfh[4][2], wfl[4][2];
    load_wfrag_split(W3, jb, lane, wfh, wfl);
    f32x4 acc[4][2];
    zero_acc(acc);
    __syncthreads();
    mfma_gemm3(sAh, sAl, wfh, wfl, acc, lane);

    // edge indices for this lane's 16 rows
    int ridx[4][4], cidx[4][4];
#pragma unroll
    for (int fr = 0; fr < 4; ++fr)
#pragma unroll
        for (int r = 0; r < 4; ++r) {
            int ge = e0 + 16 * fr + 4 * g + r;
            int gc = (ge < E) ? ge : (E - 1);
            ridx[fr][r] = row_idx[gc];
            cidx[fr][r] = col_idx[gc];
        }

    // epilogue 1: e' -> global + split bf16 into second LDS pair (fresh: no barrier)
#pragma unroll
    for (int fr = 0; fr < 4; ++fr)
#pragma unroll
        for (int c = 0; c < 2; ++c) {
            int j = jb + 16 * c + c0;
            float bej = be[j];
#pragma unroll
            for (int r = 0; r < 4; ++r) {
                int Rl = 16 * fr + 4 * g + r;
                int ge = e0 + Rl;
                float v = acc[fr][c][r]
                        + Asrc[(size_t)ridx[fr][r] * H + j]
                        + Bsrc[(size_t)cidx[fr][r] * H + j] + bej;
                v = fmaxf(v, 0.f);
                if (ge < E) eb[(size_t)ge * H + j] = v;
                int addr = (Rl << 7) + (j ^ ((Rl & 7) << 3));
                BfPair p = split2(v);
                sBh[addr] = (unsigned short)p.hi;
                sBl[addr] = (unsigned short)p.lo;
            }
        }

    load_wfrag_split(U2, jb, lane, wfh, wfl);
    zero_acc(acc);
    __syncthreads();
    mfma_gemm3(sBh, sBl, wfh, wfl, acc, lane);

    // epilogue 2: m -> scatter-add
#pragma unroll
    for (int fr = 0; fr < 4; ++fr)
#pragma unroll
        for (int c = 0; c < 2; ++c) {
            int j = jb + 16 * c + c0;
            float b1j = b1[j];
#pragma unroll
            for (int r = 0; r < 4; ++r) {
                int ge = e0 + 16 * fr + 4 * g + r;
                if (ge < E) {
                    float v = fmaxf(acc[fr][c][r] + Psrc[(size_t)ridx[fr][r] * H + j] + b1j, 0.f);
                    atomicAdd(&aggsum[(size_t)cidx[fr][r] * H + j], v);
                }
            }
        }
    // cnt: exactly once per edge -> wave 0, one lane per 4-row group
    if (w == 0 && c0 == 0) {
#pragma unroll
        for (int fr = 0; fr < 4; ++fr)
#pragma unroll
            for (int r = 0; r < 4; ++r)
                if (e0 + 16 * fr + 4 * g + r < E) atomicAdd(&cnt[cidx[fr][r]], 1.f);
    }
}

// ---------------------------------------------------------------------------
// Node update (in place): h = relu(h@V1 + (aggsum/max(cnt,1))@V2 + b2)
__global__ __launch_bounds__(256) void node_kernel(float* hb,
                                                   const float* __restrict__ aggsum,
                                                   const float* __restrict__ cnt,
                                                   const float* __restrict__ V,
                                                   const float* __restrict__ b2, int M)
{
    __shared__ __align__(16) unsigned short sAh[64 * 128];
    __shared__ __align__(16) unsigned short sAl[64 * 128];
    __shared__ __align__(16) unsigned short sBh[64 * 128];
    __shared__ __align__(16) unsigned short sBl[64 * 128];
    const int t = threadIdx.x, lane = t & 63, w = t >> 6, jb = 32 * w;
    const int r0 = blockIdx.x * 64;
    stage_split(hb, sAh, sAl, r0, M, t);
    stage_agg_split(aggsum, cnt, sBh, sBl, r0, M, t);
    short8 wfh[4][2], wfl[4][2];
    load_wfrag_split(V, jb, lane, wfh, wfl);
    f32x4 acc[4][2];
    zero_acc(acc);
    __syncthreads();
    mfma_gemm3(sAh, sAl, wfh, wfl, acc, lane);
    load_wfrag_split(V + H * H, jb, lane, wfh, wfl);
    mfma_gemm3(sBh, sBl, wfh, wfl, acc, lane);
    const int g = lane >> 4, c0 = lane & 15;
#pragma unroll
    for (int fr = 0; fr < 4; ++fr)
#pragma unroll
        for (int c = 0; c < 2; ++c) {
            int j = jb + 16 * c + c0;
            float bj = b2[j];
#pragma unroll
            for (int r = 0; r < 4; ++r) {
                int row = r0 + 16 * fr + 4 * g + r;
                if (row < M) hb[(size_t)row * H + j] = fmaxf(acc[fr][c][r] + bj, 0.f);
            }
        }
}

// ---------------------------------------------------------------------------
// Column sums + sums of squares -> atomics into sums[0:128]=Σv, sums[128:256]=Σv²
__global__ __launch_bounds__(256) void stats_kernel(const float* __restrict__ v,
                                                    int M, float* __restrict__ sums)
{
    __shared__ float red[512];
    int t = threadIdx.x;
    int j = t & 127, half = t >> 7;
    float s = 0.f, s2 = 0.f;
    for (int row = blockIdx.x * 2 + half; row < M; row += gridDim.x * 2) {
        float x = v[(size_t)row * H + j];
        s += x;
        s2 += x * x;
    }
    red[t] = s;
    red[256 + t] = s2;
    __syncthreads();
    if (t < 128) {
        atomicAdd(&sums[j],     red[t] + red[t + 128]);
        atomicAdd(&sums[H + j], red[256 + t] + red[384 + t]);
    }
}

// ---------------------------------------------------------------------------
// BatchNorm apply (training-mode batch stats), in place.
__global__ __launch_bounds__(256) void bn_kernel(float* __restrict__ v, int M,
                                                 const float* __restrict__ sums,
                                                 const float* __restrict__ g,
                                                 const float* __restrict__ b)
{
    const float invM = 1.f / (float)M;
    size_t total4 = (size_t)M * 32;
    for (size_t i = (size_t)blockIdx.x * 256 + threadIdx.x; i < total4;
         i += (size_t)gridDim.x * 256) {
        int j0 = (int)(i & 31) * 4;
        float4 x = reinterpret_cast<float4*>(v)[i];
        float* px = &x.x;
#pragma unroll
        for (int c = 0; c < 4; ++c) {
            int j = j0 + c;
            float mean = sums[j] * invM;
            float var  = sums[H + j] * invM - mean * mean;
            float sc   = rsqrtf(var + 1e-5f) * g[j];
            px[c] = (px[c] - mean) * sc + b[j];
        }
        reinterpret_cast<float4*>(v)[i] = x;
    }
}

// ---------------------------------------------------------------------------
// Final readout: out = [mean(h) | mean(e)] @ reg_w + reg_b
__global__ __launch_bounds__(256) void final_kernel(const float* __restrict__ hsum,
                                                    const float* __restrict__ esum,
                                                    const float* __restrict__ reg_w,
                                                    const float* __restrict__ reg_b,
                                                    float* __restrict__ out,
                                                    float invN, float invE)
{
    __shared__ float red[256];
    int t = threadIdx.x;
    float v = (t < 128) ? hsum[t] * invN * reg_w[t]
                        : esum[t - 128] * invE * reg_w[t];
    red[t] = v;
    __syncthreads();
    for (int s = 128; s > 0; s >>= 1) {
        if (t < s) red[t] += red[t + s];
        __syncthreads();
    }
    if (t == 0) out[0] = red[0] + reg_b[0];
}

// ---------------------------------------------------------------------------
extern "C" void kernel_launch(void* const* d_in, const int* in_sizes, int n_in,
                              void* d_out, int out_size, void* d_ws, size_t ws_size,
                              hipStream_t stream)
{
    const float* x          = (const float*)d_in[0];
    const int*   edge_index = (const int*)  d_in[1];
    const float* edge_attr  = (const float*)d_in[2];
    const float* enc_node_w = (const float*)d_in[3];
    const float* enc_node_b = (const float*)d_in[4];
    const float* enc_edge_w = (const float*)d_in[5];
    const float* enc_edge_b = (const float*)d_in[6];
    const float* edge_w     = (const float*)d_in[7];
    const float* edge_b     = (const float*)d_in[8];
    const float* n1_w       = (const float*)d_in[9];
    const float* n1_b       = (const float*)d_in[10];
    const float* n2_w       = (const float*)d_in[11];
    const float* n2_b       = (const float*)d_in[12];
    const float* bn_node_g  = (const float*)d_in[13];
    const float* bn_node_b  = (const float*)d_in[14];
    const float* bn_edge_g  = (const float*)d_in[15];
    const float* bn_edge_b  = (const float*)d_in[16];
    const float* reg_w      = (const float*)d_in[17];
    const float* reg_b      = (const float*)d_in[18];

    const int N = in_sizes[0] / F_IN;
    const int E = in_sizes[1] / 2;
    const size_t NH = (size_t)N * H;
    const size_t EH = (size_t)E * H;

    float* ws     = (float*)d_ws;
    float* hbuf   = ws;                 // [N,128]  (in place across layers)
    float* ebuf   = hbuf + NH;          // [E,128]  (in place across layers)
    float* Abuf   = ebuf + EH;          // [N,128]
    float* Bbuf   = Abuf + NH;          // [N,128]
    float* Pbuf   = Bbuf + NH;          // [N,128]
    float* aggsum = Pbuf + NH;          // [N,128]
    float* cnt    = aggsum + NH;        // [N]
    float* stats  = cnt + N;            // hsum[128],hsumsq[128],esum[128],esumsq[128]

    const int* row_idx = edge_index;
    const int* col_idx = edge_index + E;

    enc_kernel<<<(N + 1) / 2, 256, 0, stream>>>(x, enc_node_w, enc_node_b, hbuf, N);
    enc_kernel<<<(E + 1) / 2, 256, 0, stream>>>(edge_attr, enc_edge_w, enc_edge_b, ebuf, E);

    const int nodeBlocks = (N + 63) / 64;
    const int edgeBlocks = (E + 63) / 64;

    for (int i = 0; i < 3; ++i) {
        (void)hipMemsetAsync(aggsum, 0, (NH + (size_t)N + 512) * sizeof(float), stream);
        abp_kernel<<<nodeBlocks, 256, 0, stream>>>(
            hbuf, edge_w + (size_t)i * 384 * H, n1_w + (size_t)i * 256 * H,
            Abuf, Bbuf, Pbuf, N);
        edge_kernel<<<edgeBlocks, 256, 0, stream>>>(
            ebuf, row_idx, col_idx, Abuf, Bbuf, Pbuf,
            edge_w + (size_t)i * 384 * H + 256 * H,
            n1_w + (size_t)i * 256 * H + 128 * H,
            edge_b + i * H, n1_b + i * H,
            aggsum, cnt, E);
        node_kernel<<<nodeBlocks, 256, 0, stream>>>(
            hbuf, aggsum, cnt, n2_w + (size_t)i * 256 * H, n2_b + i * H, N);
        stats_kernel<<<512, 256, 0, stream>>>(hbuf, N, stats);
        stats_kernel<<<512, 256, 0, stream>>>(ebuf, E, stats + 256);
        if (i < 2) {
            bn_kernel<<<1024, 256, 0, stream>>>(hbuf, N, stats,       bn_node_g, bn_node_b);
            bn_kernel<<<2048, 256, 0, stream>>>(ebuf, E, stats + 256, bn_edge_g, bn_edge_b);
        }
    }
    final_kernel<<<1, 256, 0, stream>>>(stats, stats + 256, reg_w, reg_b,
                                        (float*)d_out, 1.f / (float)N, 1.f / (float)E);
}